// Round 1
// baseline (206.741 us; speedup 1.0000x reference)
//
#include <hip/hip_runtime.h>

// skipConnection: out[i] = in[i,0]*w + in[i,1]*(1-w)
// Memory-bound elementwise. 4 outputs / thread: 2x float4 load, 1x float4 store.

__global__ __launch_bounds__(256) void skipConnection_kernel(
    const float4* __restrict__ in,   // [N/2] float4 = [N] (x,y) pairs packed 2-per-float4
    const float* __restrict__ wp,    // device scalar weight
    float4* __restrict__ out,        // [N/4] float4 outputs
    int n4)                          // N/4
{
    int i = blockIdx.x * blockDim.x + threadIdx.x;
    if (i >= n4) return;

    const float w  = wp[0];
    const float wm = 1.0f - w;

    // lane reads 32 contiguous bytes: pairs (4i..4i+3)
    float4 a = in[2 * i];       // pairs 4i, 4i+1  -> (x0,y0,x1,y1)
    float4 b = in[2 * i + 1];   // pairs 4i+2,4i+3 -> (x2,y2,x3,y3)

    float4 o;
    o.x = fmaf(a.x, w, a.y * wm);
    o.y = fmaf(a.z, w, a.w * wm);
    o.z = fmaf(b.x, w, b.y * wm);
    o.w = fmaf(b.z, w, b.w * wm);

    out[i] = o;
}

extern "C" void kernel_launch(void* const* d_in, const int* in_sizes, int n_in,
                              void* d_out, int out_size, void* d_ws, size_t ws_size,
                              hipStream_t stream) {
    const float* in = (const float*)d_in[0];   // [N,2] fp32
    const float* wp = (const float*)d_in[1];   // [1,1] fp32
    float* out      = (float*)d_out;           // [N,1] fp32

    int n  = out_size;        // N = 16777216
    int n4 = n / 4;           // N divisible by 4
    int block = 256;
    int grid  = (n4 + block - 1) / block;

    skipConnection_kernel<<<grid, block, 0, stream>>>(
        (const float4*)in, wp, (float4*)out, n4);
}

// Round 3
// 200.123 us; speedup vs baseline: 1.0331x; 1.0331x over previous
//
#include <hip/hip_runtime.h>

// skipConnection: out[i] = in[i,0]*w + in[i,1]*(1-w)
// Memory-bound elementwise. 192 MiB mandatory HBM traffic -> ~30 us floor.
// 4 outputs / thread: 2x 16B nontemporal load, 1x 16B nontemporal store.

typedef float v4f __attribute__((ext_vector_type(4)));  // native vector: legal for nontemporal builtins

__global__ __launch_bounds__(256) void skipConnection_kernel(
    const v4f* __restrict__ in,   // [N/2] v4f = [N] (x,y) pairs packed 2-per-vec
    const float* __restrict__ wp, // device scalar weight
    v4f* __restrict__ out,        // [N/4] v4f outputs
    int n4)                       // N/4
{
    int i = blockIdx.x * blockDim.x + threadIdx.x;
    if (i >= n4) return;

    const float w  = wp[0];
    const float wm = 1.0f - w;

    // lane reads 32 contiguous bytes: pairs (4i..4i+3). Streaming, zero reuse -> nt.
    v4f a = __builtin_nontemporal_load(&in[2 * i]);     // (x0,y0,x1,y1)
    v4f b = __builtin_nontemporal_load(&in[2 * i + 1]); // (x2,y2,x3,y3)

    v4f o;
    o.x = fmaf(a.x, w, a.y * wm);
    o.y = fmaf(a.z, w, a.w * wm);
    o.z = fmaf(b.x, w, b.y * wm);
    o.w = fmaf(b.z, w, b.w * wm);

    __builtin_nontemporal_store(o, &out[i]);
}

extern "C" void kernel_launch(void* const* d_in, const int* in_sizes, int n_in,
                              void* d_out, int out_size, void* d_ws, size_t ws_size,
                              hipStream_t stream) {
    const float* in = (const float*)d_in[0];   // [N,2] fp32
    const float* wp = (const float*)d_in[1];   // [1,1] fp32
    float* out      = (float*)d_out;           // [N,1] fp32

    int n  = out_size;        // N = 16777216
    int n4 = n / 4;           // N divisible by 4
    int block = 256;
    int grid  = (n4 + block - 1) / block;

    skipConnection_kernel<<<grid, block, 0, stream>>>(
        (const v4f*)in, wp, (v4f*)out, n4);
}